// Round 7
// baseline (903.822 us; speedup 1.0000x reference)
//
#include <hip/hip_runtime.h>
#include <cstdint>
#include <cstddef>

#define DEVI __device__ __forceinline__

typedef __attribute__((ext_vector_type(8))) short short8;   // 8 bf16 = 4 VGPRs
typedef __attribute__((ext_vector_type(4))) float float4v;  // MFMA acc

DEVI float silu_f(float x) { return x / (1.f + __expf(-x)); }
DEVI float clip5(float x) { return fminf(fmaxf(x, -5.f), 5.f); }

DEVI unsigned short f2bf(float f) {
    union { float f; unsigned u; } x{f};
    unsigned r = x.u + 0x7FFF + ((x.u >> 16) & 1);  // RNE
    return (unsigned short)(r >> 16);
}
DEVI unsigned pack2(float a, float b) {
    return (unsigned)f2bf(a) | ((unsigned)f2bf(b) << 16);
}

// ---------------------------------------------------------------------------
// Weight pre-convert: src[K][N] fp32 -> dst[N][K] bf16 (transposed), 10 mats.
// ---------------------------------------------------------------------------
struct WDesc { const float* src; unsigned short* dst; int K; int N; };
struct WPack { WDesc d[10]; };

__global__ __launch_bounds__(256) void cvt_all_k(WPack p) {
    const WDesc w = p.d[blockIdx.y];
    const int total = w.K * w.N;
    const int ln = (w.N == 256) ? 8 : 7;  // N is 128 or 256
    const int nm = w.N - 1;
    for (int idx = blockIdx.x * 256 + threadIdx.x; idx < total; idx += gridDim.x * 256) {
        int k = idx >> ln, n = idx & nm;
        w.dst[(size_t)n * w.K + k] = f2bf(w.src[idx]);
    }
}

// ---------------------------------------------------------------------------
// Shared MFMA helpers (4-wave block, M-tile 128, N 128, per-wave 32x128).
// Acc layout: row = w*32 + mt*16 + laneq*4 + r, col = nt*16 + lanem.
// ---------------------------------------------------------------------------
template <int LDA>
DEVI void mfma64s(const short* A, const short* B, int w, int lanem, int laneq,
                  float4v acc[2][8]) {
#pragma unroll
    for (int s = 0; s < 2; s++) {
        const int ko = s * 32 + laneq * 8;
        short8 bfr[8];
#pragma unroll
        for (int nt = 0; nt < 8; nt++)
            bfr[nt] = *(const short8*)(B + (nt * 16 + lanem) * 72 + ko);
#pragma unroll
        for (int mt = 0; mt < 2; mt++) {
            short8 af = *(const short8*)(A + (w * 32 + mt * 16 + lanem) * LDA + ko);
#pragma unroll
            for (int nt = 0; nt < 8; nt++)
                acc[mt][nt] = __builtin_amdgcn_mfma_f32_16x16x32_bf16(
                    af, bfr[nt], acc[mt][nt], 0, 0, 0);
        }
    }
}

DEVI void stageB(short* Bls, const short* WT, int ldw, int koff, int sm, int h) {
    const uint4* bs = (const uint4*)(WT + (size_t)sm * ldw + koff + h * 32);
    uint4* bd = (uint4*)(Bls + sm * 72 + h * 32);
#pragma unroll
    for (int i = 0; i < 4; i++) bd[i] = bs[i];
}

// pack acc-fragment cols [ntb*16, ntb*16+64) -> A LDS (cols 0..63, stride LDA)
// ntb MUST be compile-time (callers unroll) so acc stays in VGPRs.
template <int LDA>
DEVI void packA(short* Als, const float4v a[2][8], int ntb, int w, int lanem, int laneq) {
#pragma unroll
    for (int mt = 0; mt < 2; mt++)
#pragma unroll
        for (int r = 0; r < 4; r++) {
            const int row = w * 32 + mt * 16 + laneq * 4 + r;
#pragma unroll
            for (int nt0 = 0; nt0 < 4; nt0++)
                Als[row * LDA + nt0 * 16 + lanem] = (short)f2bf(a[mt][ntb + nt0][r]);
        }
}

// ---------------------------------------------------------------------------
// QKV fused: stage LN1(node) once -> Xls, then 3 GEMMs (Wq,Wk,Wv).
// redS/redQ aliased into Bls (reads complete before first Bls stage write,
// separated by the post-LN __syncthreads). LDS 53248B -> 3 blocks/CU.
// ---------------------------------------------------------------------------
__global__ __launch_bounds__(256, 2) void qkv_k(
    const float* __restrict__ X, int M,
    const short* __restrict__ W0, const short* __restrict__ W1, const short* __restrict__ W2,
    const float* __restrict__ g, const float* __restrict__ b,
    float* __restrict__ o0, float* __restrict__ o1, float* __restrict__ o2)
{
    __shared__ short Xls[128 * 136];
    __shared__ short Bls[128 * 72];
    float* redS = (float*)Bls;      // aliased: used only pre-first-stage
    float* redQ = redS + 256;

    const int tid = threadIdx.x, l = tid & 63, w = tid >> 6;
    const int lanem = l & 15, laneq = l >> 4;
    const int rbase = blockIdx.x * 128;
    const int sm = tid >> 1, h = tid & 1;
    const int grow = rbase + sm;
    const bool rowok = grow < M;

    // LN stats + stage (single X read: keep row-half in regs)
    {
        float4 v[16];
        const float* xr = X + (size_t)grow * 128 + h * 64;
        float s = 0.f, q = 0.f;
#pragma unroll
        for (int i = 0; i < 16; i++) {
            v[i] = rowok ? *(const float4*)(xr + i * 4) : make_float4(0.f, 0.f, 0.f, 0.f);
            s += v[i].x + v[i].y + v[i].z + v[i].w;
            q += v[i].x * v[i].x + v[i].y * v[i].y + v[i].z * v[i].z + v[i].w * v[i].w;
        }
        redS[tid] = s; redQ[tid] = q;
        __syncthreads();
        float ts = redS[sm * 2] + redS[sm * 2 + 1];
        float tq = redQ[sm * 2] + redQ[sm * 2 + 1];
        float mu = ts * (1.f / 128.f);
        float var = tq * (1.f / 128.f) - mu * mu;
        float rstd = rsqrtf(var + 1e-5f);
#pragma unroll
        for (int i = 0; i < 16; i++) {
            int c = h * 64 + i * 4;
            float4 g4 = *(const float4*)(g + c);
            float4 b4 = *(const float4*)(b + c);
            v[i].x = (v[i].x - mu) * rstd * g4.x + b4.x;
            v[i].y = (v[i].y - mu) * rstd * g4.y + b4.y;
            v[i].z = (v[i].z - mu) * rstd * g4.z + b4.z;
            v[i].w = (v[i].w - mu) * rstd * g4.w + b4.w;
        }
        uint4* xd = (uint4*)(Xls + sm * 136 + h * 64);
#pragma unroll
        for (int i = 0; i < 8; i++) {
            uint4 o;
            o.x = pack2(v[i * 2].x, v[i * 2].y);
            o.y = pack2(v[i * 2].z, v[i * 2].w);
            o.z = pack2(v[i * 2 + 1].x, v[i * 2 + 1].y);
            o.w = pack2(v[i * 2 + 1].z, v[i * 2 + 1].w);
            xd[i] = o;
        }
    }
    __syncthreads();   // redS reads + Xls writes complete before Bls staging

    const short* Ws[3] = {W0, W1, W2};
    float* outs[3] = {o0, o1, o2};
#pragma unroll
    for (int j = 0; j < 3; j++) {
        float4v acc[2][8];
#pragma unroll
        for (int mt = 0; mt < 2; mt++)
#pragma unroll
            for (int nt = 0; nt < 8; nt++) acc[mt][nt] = (float4v){0.f, 0.f, 0.f, 0.f};
#pragma unroll
        for (int k0 = 0; k0 < 128; k0 += 64) {
            stageB(Bls, Ws[j], 128, k0, sm, h);
            __syncthreads();
            mfma64s<136>(Xls + k0, Bls, w, lanem, laneq, acc);
            __syncthreads();
        }
        float* oj = outs[j];
#pragma unroll
        for (int mt = 0; mt < 2; mt++)
#pragma unroll
            for (int nt = 0; nt < 8; nt++) {
                const int gc = nt * 16 + lanem;
#pragma unroll
                for (int r = 0; r < 4; r++) {
                    int gr = rbase + w * 32 + mt * 16 + laneq * 4 + r;
                    if (gr < M) oj[(size_t)gr * 128 + gc] = acc[mt][nt][r];
                }
            }
    }
}

// ---------------------------------------------------------------------------
// MEGA kernel (round-3 proven structure, 4 waves, wave tile 32x128).
// EDGE=true : X=edgef. LN1 -> PE=@We -> score(clip(QK/4)*PE, wE out)
//             -> e2 = edgef + score@Wo + bo -> in-reg LN2 -> FFN -> e_out.
// EDGE=false: X=wVd.   h2 = node + X@Wo + bo -> in-reg LN2 -> FFN -> h_out.
// redS/redQ aliased into Bls (EDGE Phase A only; extra barrier added before
// the first Bls staging write). LDS 53248B -> 3 blocks/CU.
// ---------------------------------------------------------------------------
template <bool EDGE>
__global__ __launch_bounds__(256, 2) void mega_k(
    const float* __restrict__ X, const float* __restrict__ resid, int M,
    const int* __restrict__ eidx, int E,
    const float* __restrict__ Qm, const float* __restrict__ Km,
    const short* __restrict__ WgT, const short* __restrict__ WoT,
    const short* __restrict__ W1T, const short* __restrict__ W2T,
    const float* __restrict__ g1, const float* __restrict__ b1,
    const float* __restrict__ g2, const float* __restrict__ b2,
    const float* __restrict__ bo, float* __restrict__ wE,
    float* __restrict__ out)
{
    __shared__ short Xls[128 * 136];   // A operand / staged X / staged hn
    __shared__ short Bls[128 * 72];
    float* redS = (float*)Bls;         // aliased: EDGE Phase A only
    float* redQ = redS + 256;

    const int tid = threadIdx.x, l = tid & 63, w = tid >> 6;
    const int lanem = l & 15, laneq = l >> 4;
    const int rbase = blockIdx.x * 128;
    const int sm = tid >> 1, h = tid & 1;
    const int grow = rbase + sm;
    const bool rowok = grow < M;

    float4v accS[2][8];  // EDGE: PE then score
    float4v e2a[2][8];   // proj acc -> e2/h2 -> final out (GEMM2 accumulates)

    // ---- Phase A+B (EDGE): LN1 (single X read) + GEMM0 (PE = LN1(X) @ We) ----
    if constexpr (EDGE) {
        {
            float4 v[16];
            const float* xr = X + (size_t)grow * 128 + h * 64;
            float s = 0.f, q = 0.f;
#pragma unroll
            for (int i = 0; i < 16; i++) {
                v[i] = rowok ? *(const float4*)(xr + i * 4) : make_float4(0.f, 0.f, 0.f, 0.f);
                s += v[i].x + v[i].y + v[i].z + v[i].w;
                q += v[i].x * v[i].x + v[i].y * v[i].y + v[i].z * v[i].z + v[i].w * v[i].w;
            }
            redS[tid] = s; redQ[tid] = q;
            __syncthreads();
            float ts = redS[sm * 2] + redS[sm * 2 + 1];
            float tq = redQ[sm * 2] + redQ[sm * 2 + 1];
            float mu1 = ts * (1.f / 128.f);
            float var1 = tq * (1.f / 128.f) - mu1 * mu1;
            float rstd1 = rsqrtf(var1 + 1e-5f);
#pragma unroll
            for (int i = 0; i < 16; i++) {
                int c = h * 64 + i * 4;
                float4 g4 = *(const float4*)(g1 + c);
                float4 b4 = *(const float4*)(b1 + c);
                v[i].x = (v[i].x - mu1) * rstd1 * g4.x + b4.x;
                v[i].y = (v[i].y - mu1) * rstd1 * g4.y + b4.y;
                v[i].z = (v[i].z - mu1) * rstd1 * g4.z + b4.z;
                v[i].w = (v[i].w - mu1) * rstd1 * g4.w + b4.w;
            }
            uint4* xd = (uint4*)(Xls + sm * 136 + h * 64);
#pragma unroll
            for (int i = 0; i < 8; i++) {
                uint4 o;
                o.x = pack2(v[i * 2].x, v[i * 2].y);
                o.y = pack2(v[i * 2].z, v[i * 2].w);
                o.z = pack2(v[i * 2 + 1].x, v[i * 2 + 1].y);
                o.w = pack2(v[i * 2 + 1].z, v[i * 2 + 1].w);
                xd[i] = o;
            }
        }
        __syncthreads();   // NEW: redS/redQ reads done before Bls staging below

#pragma unroll
        for (int mt = 0; mt < 2; mt++)
#pragma unroll
            for (int nt = 0; nt < 8; nt++) accS[mt][nt] = (float4v){0.f, 0.f, 0.f, 0.f};

#pragma unroll
        for (int k0 = 0; k0 < 128; k0 += 64) {
            stageB(Bls, WgT, 128, k0, sm, h);
            __syncthreads();
            mfma64s<136>(Xls + k0, Bls, w, lanem, laneq, accS);
            __syncthreads();
        }

        // ---- Phase C: score = clip(K[src]*Q[dst]/4)*PE (in acc), wE out ----
#pragma unroll
        for (int mt = 0; mt < 2; mt++)
#pragma unroll
            for (int r = 0; r < 4; r++) {
                const int row = w * 32 + mt * 16 + laneq * 4 + r;
                const int e = rbase + row;
                const bool ok = e < M;
                const int si = ok ? eidx[e] : 0;
                const int di = ok ? eidx[(size_t)E + e] : 0;
                const float* qr = Qm + (size_t)di * 128;
                const float* kr = Km + (size_t)si * 128;
                float hs[8];
#pragma unroll
                for (int nt = 0; nt < 8; nt++) {
                    const int gc = nt * 16 + lanem;
                    float sv = clip5(kr[gc] * qr[gc] * 0.25f) * accS[mt][nt][r];
                    accS[mt][nt][r] = sv;
                    hs[nt] = sv;
                }
#pragma unroll
                for (int nt = 0; nt < 8; nt++) {
                    hs[nt] += __shfl_xor(hs[nt], 1, 64);
                    hs[nt] += __shfl_xor(hs[nt], 2, 64);
                    hs[nt] += __shfl_xor(hs[nt], 4, 64);
                    hs[nt] += __shfl_xor(hs[nt], 8, 64);
                }
                if (lanem == 0 && ok) {
                    float4 wa, wb;
                    wa.x = __expf(clip5(hs[0])); wa.y = __expf(clip5(hs[1]));
                    wa.z = __expf(clip5(hs[2])); wa.w = __expf(clip5(hs[3]));
                    wb.x = __expf(clip5(hs[4])); wb.y = __expf(clip5(hs[5]));
                    wb.z = __expf(clip5(hs[6])); wb.w = __expf(clip5(hs[7]));
                    *(float4*)(wE + (size_t)e * 8) = wa;
                    *(float4*)(wE + (size_t)e * 8 + 4) = wb;
                }
            }
    } else {
        // NODE: stage raw X once into Xls (both halves)
#pragma unroll
        for (int k0 = 0; k0 < 128; k0 += 64) {
            const int kb = k0 + h * 32;
            const float* xr2 = X + (size_t)grow * 128 + kb;
            float4 v[8];
#pragma unroll
            for (int i = 0; i < 8; i++)
                v[i] = rowok ? *(const float4*)(xr2 + i * 4) : make_float4(0.f, 0.f, 0.f, 0.f);
            uint4* ad = (uint4*)(Xls + sm * 136 + kb);
#pragma unroll
            for (int i = 0; i < 4; i++) {
                uint4 o;
                o.x = pack2(v[i * 2].x, v[i * 2].y);
                o.y = pack2(v[i * 2].z, v[i * 2].w);
                o.z = pack2(v[i * 2 + 1].x, v[i * 2 + 1].y);
                o.w = pack2(v[i * 2 + 1].z, v[i * 2 + 1].w);
                ad[i] = o;
            }
        }
    }

    // ---- Phase D: proj GEMM (A = score [EDGE] or staged X [NODE]) @ WoT ----
#pragma unroll
    for (int mt = 0; mt < 2; mt++)
#pragma unroll
        for (int nt = 0; nt < 8; nt++) e2a[mt][nt] = (float4v){0.f, 0.f, 0.f, 0.f};

#pragma unroll
    for (int k0 = 0; k0 < 128; k0 += 64) {
        if constexpr (EDGE) {
            packA<136>(Xls, accS, k0 >> 4, w, lanem, laneq);  // cols 0..63
        }
        stageB(Bls, WoT, 128, k0, sm, h);
        __syncthreads();
        if constexpr (EDGE)
            mfma64s<136>(Xls, Bls, w, lanem, laneq, e2a);
        else
            mfma64s<136>(Xls + k0, Bls, w, lanem, laneq, e2a);
        __syncthreads();
    }

    // ---- Phase E: e2 = resid + proj + bo; in-register LN2 stats ----
    float mur[2][4], rsr[2][4];
#pragma unroll
    for (int mt = 0; mt < 2; mt++)
#pragma unroll
        for (int r = 0; r < 4; r++) {
            const int row = w * 32 + mt * 16 + laneq * 4 + r;
            const int gr = rbase + row;
            const bool ok = gr < M;
            float s = 0.f, q = 0.f;
#pragma unroll
            for (int nt = 0; nt < 8; nt++) {
                const int gc = nt * 16 + lanem;
                float rv = ok ? resid[(size_t)gr * 128 + gc] : 0.f;
                float x = rv + e2a[mt][nt][r] + bo[gc];
                e2a[mt][nt][r] = x;
                s += x; q += x * x;
            }
            s += __shfl_xor(s, 1, 64); q += __shfl_xor(q, 1, 64);
            s += __shfl_xor(s, 2, 64); q += __shfl_xor(q, 2, 64);
            s += __shfl_xor(s, 4, 64); q += __shfl_xor(q, 4, 64);
            s += __shfl_xor(s, 8, 64); q += __shfl_xor(q, 8, 64);
            float mu = s * (1.f / 128.f);
            float var = q * (1.f / 128.f) - mu * mu;
            mur[mt][r] = mu;
            rsr[mt][r] = rsqrtf(var + 1e-5f);
        }

    // ---- Phase F: pack hn = LN2(e2) fully into Xls (frees LN state) ----
#pragma unroll
    for (int mt = 0; mt < 2; mt++)
#pragma unroll
        for (int r = 0; r < 4; r++) {
            const int row = w * 32 + mt * 16 + laneq * 4 + r;
            const float muv = mur[mt][r], rv = rsr[mt][r];
#pragma unroll
            for (int nt = 0; nt < 8; nt++) {
                const int gc = nt * 16 + lanem;
                float hnv = (e2a[mt][nt][r] - muv) * rv * g2[gc] + b2[gc];
                Xls[row * 136 + gc] = (short)f2bf(hnv);
            }
        }

    // ---- GEMM1 both halves: acc2[hh] = hn @ W1half ----
    float4v acc2[2][2][8];
#pragma unroll
    for (int hh = 0; hh < 2; hh++)
#pragma unroll
        for (int mt = 0; mt < 2; mt++)
#pragma unroll
            for (int nt = 0; nt < 8; nt++) acc2[hh][mt][nt] = (float4v){0.f, 0.f, 0.f, 0.f};

#pragma unroll
    for (int hh = 0; hh < 2; hh++) {
        const short* w1b = W1T + hh * 16384;
#pragma unroll
        for (int k0 = 0; k0 < 128; k0 += 64) {
            stageB(Bls, w1b, 128, k0, sm, h);
            __syncthreads();
            mfma64s<136>(Xls + k0, Bls, w, lanem, laneq, acc2[hh]);
            __syncthreads();
        }
    }

    // silu
#pragma unroll
    for (int hh = 0; hh < 2; hh++)
#pragma unroll
        for (int mt = 0; mt < 2; mt++)
#pragma unroll
            for (int nt = 0; nt < 8; nt++)
#pragma unroll
                for (int r = 0; r < 4; r++)
                    acc2[hh][mt][nt][r] = silu_f(acc2[hh][mt][nt][r]);

    // ---- GEMM2: e2a += silu(t) @ W2 (accumulate into residual acc) ----
#pragma unroll
    for (int hh = 0; hh < 2; hh++) {
#pragma unroll
        for (int k0 = 0; k0 < 128; k0 += 64) {
            packA<136>(Xls, acc2[hh], k0 >> 4, w, lanem, laneq);  // cols 0..63
            stageB(Bls, W2T, 256, hh * 128 + k0, sm, h);
            __syncthreads();
            mfma64s<136>(Xls, Bls, w, lanem, laneq, e2a);
            __syncthreads();
        }
    }

    // ---- epilogue: out = e2a ----
#pragma unroll
    for (int mt = 0; mt < 2; mt++)
#pragma unroll
        for (int nt = 0; nt < 8; nt++) {
            const int gc = nt * 16 + lanem;
#pragma unroll
            for (int r = 0; r < 4; r++) {
                const int gr = rbase + w * 32 + mt * 16 + laneq * 4 + r;
                if (gr < M) out[(size_t)gr * 128 + gc] = e2a[mt][nt][r];
            }
        }
}

// ---------------------------------------------------------------------------
// CSR-by-dst build: count -> 2-level exclusive scan -> scatter (src,eid)
// ---------------------------------------------------------------------------
__global__ __launch_bounds__(256) void count_k(
    const int* __restrict__ eidx, int* __restrict__ deg, int E)
{
    int e = blockIdx.x * 256 + threadIdx.x;
    if (e < E) atomicAdd(&deg[eidx[(size_t)E + e]], 1);
}

__global__ __launch_bounds__(256) void scan_part_k(
    const int* __restrict__ deg, int* __restrict__ psum, int Nn)
{
    __shared__ int red[256];
    int i = blockIdx.x * 256 + threadIdx.x;
    red[threadIdx.x] = (i < Nn) ? deg[i] : 0;
    __syncthreads();
    for (int s = 128; s > 0; s >>= 1) {
        if (threadIdx.x < s) red[threadIdx.x] += red[threadIdx.x + s];
        __syncthreads();
    }
    if (threadIdx.x == 0) psum[blockIdx.x] = red[0];
}

__global__ __launch_bounds__(1024) void scan_mid_k(int* __restrict__ psum, int P)
{
    __shared__ int sm[1024];
    int t = threadIdx.x;
    int v = (t < P) ? psum[t] : 0;
    sm[t] = v;
    __syncthreads();
    for (int ofs = 1; ofs < 1024; ofs <<= 1) {
        int x = sm[t];
        if (t >= ofs) x += sm[t - ofs];
        __syncthreads();
        sm[t] = x;
        __syncthreads();
    }
    if (t < P) psum[t] = sm[t] - v;  // exclusive
}

__global__ __launch_bounds__(256) void scan_fin_k(
    int* __restrict__ deg_cur, const int* __restrict__ psum,
    int* __restrict__ rs, int Nn)
{
    __shared__ int sm[256];
    int i = blockIdx.x * 256 + threadIdx.x;
    int t = threadIdx.x;
    int v = (i < Nn) ? deg_cur[i] : 0;
    sm[t] = v;
    __syncthreads();
    for (int ofs = 1; ofs < 256; ofs <<= 1) {
        int x = sm[t];
        if (t >= ofs) x += sm[t - ofs];
        __syncthreads();
        sm[t] = x;
        __syncthreads();
    }
    if (i < Nn) {
        int excl = sm[t] - v + psum[blockIdx.x];
        rs[i] = excl;
        deg_cur[i] = excl;            // cursor for scatter
        if (i == Nn - 1) rs[Nn] = excl + v;
    }
}

__global__ __launch_bounds__(256) void scatter_k(
    const int* __restrict__ eidx, int* __restrict__ cur,
    int2* __restrict__ csr, int E)
{
    int e = blockIdx.x * 256 + threadIdx.x;
    if (e >= E) return;
    int d = eidx[(size_t)E + e];
    int pos = atomicAdd(&cur[d], 1);
    csr[pos] = make_int2(eidx[e], e);  // (src, eid)
}

// ---------------------------------------------------------------------------
// Node aggregation: per dst node, sum w*V[src] and z over its CSR edge list,
// write wV/(z+1e-6). 32 lanes/node, register accumulation, no atomics.
// ---------------------------------------------------------------------------
__global__ __launch_bounds__(256) void agg_k(
    const float* __restrict__ V, const float* __restrict__ wE,
    const int2* __restrict__ csr, const int* __restrict__ rs,
    float* __restrict__ out, int Nn)
{
    int n = blockIdx.x * 8 + (threadIdx.x >> 5);
    if (n >= Nn) return;
    int lane = threadIdx.x & 31;
    int h = lane >> 2;
    int b = rs[n], eend = rs[n + 1];
    float ax = 0.f, ay = 0.f, az = 0.f, aw = 0.f, zs = 0.f;
    for (int i = b; i < eend; i++) {
        int2 pr = csr[i];
        float w = wE[(size_t)pr.y * 8 + h];
        float4 vv = *(const float4*)(V + (size_t)pr.x * 128 + (size_t)lane * 4);
        ax += w * vv.x; ay += w * vv.y; az += w * vv.z; aw += w * vv.w;
        zs += w;
    }
    float rz = 1.f / (zs + 1e-6f);
    *(float4*)(out + (size_t)n * 128 + (size_t)lane * 4) =
        make_float4(ax * rz, ay * rz, az * rz, aw * rz);
}

// ---------------------------------------------------------------------------
extern "C" void kernel_launch(void* const* d_in, const int* in_sizes, int n_in,
                              void* d_out, int out_size, void* d_ws, size_t ws_size,
                              hipStream_t stream)
{
    const float* node  = (const float*)d_in[0];
    const float* edgef = (const float*)d_in[1];
    const int*   eidx  = (const int*)d_in[2];
    const float* Wq = (const float*)d_in[3];
    const float* Wk = (const float*)d_in[4];
    const float* Wv = (const float*)d_in[5];
    const float* We = (const float*)d_in[6];
    const float* Wo_n = (const float*)d_in[7];
    const float* bo_n = (const float*)d_in[8];
    const float* Wo_e = (const float*)d_in[9];
    const float* bo_e = (const float*)d_in[10];
    const float* W1n = (const float*)d_in[11];
    const float* W2n = (const float*)d_in[12];
    const float* W1e = (const float*)d_in[13];
    const float* W2e = (const float*)d_in[14];
    const float* g1n = (const float*)d_in[15];
    const float* b1n = (const float*)d_in[16];
    const float* g1e = (const float*)d_in[17];
    const float* b1e = (const float*)d_in[18];
    const float* g2n = (const float*)d_in[19];
    const float* b2n = (const float*)d_in[20];
    const float* g2e = (const float*)d_in[21];
    const float* b2e = (const float*)d_in[22];

    const int N = in_sizes[0] / 128;
    const int E = in_sizes[1] / 128;
    float* outn = (float*)d_out;                    // node out
    float* oute = (float*)d_out + (size_t)N * 128;  // edge out

    // ---- workspace: bf16 transposed weights first, then fp32/int buffers ----
    unsigned short* wts = (unsigned short*)d_ws;
    unsigned short* WqT  = wts;            // 128x128
    unsigned short* WkT  = wts + 16384;
    unsigned short* WvT  = wts + 32768;
    unsigned short* WeT  = wts + 49152;
    unsigned short* WonT = wts + 65536;
    unsigned short* WoeT = wts + 81920;
    unsigned short* W1nT = wts + 98304;    // 256x128
    unsigned short* W1eT = wts + 131072;   // 256x128
    unsigned short* W2nT = wts + 163840;   // 128x256
    unsigned short* W2eT = wts + 196608;   // 128x256  (end: 229376 shorts)
    float* p = (float*)(wts + 229376);
    float* Qb  = p; p += (size_t)N * 128;
    float* Kb  = p; p += (size_t)N * 128;
    float* Vb  = p; p += (size_t)N * 128;
    float* wVd = p; p += (size_t)N * 128;   // divided aggregation result
    float* wEb = p; p += (size_t)E * 8;     // per-edge per-head weights
    int* rs   = (int*)p;                    // rowstart, N+1
    int* cur  = rs + (N + 1);               // degree / scatter cursor, N
    int* psum = cur + N;                    // partial sums, up to 1024
    int* csr_i = psum + 1024;
    csr_i = (int*)(((uintptr_t)csr_i + 15) & ~(uintptr_t)15);
    int2* csr = (int2*)csr_i;               // E entries (src, eid)

    // ---- weight conversion (one launch, 10 matrices) ----
    {
        WPack pk;
        pk.d[0] = {Wq,   WqT,  128, 128}; pk.d[1] = {Wk,   WkT,  128, 128};
        pk.d[2] = {Wv,   WvT,  128, 128}; pk.d[3] = {We,   WeT,  128, 128};
        pk.d[4] = {Wo_n, WonT, 128, 128}; pk.d[5] = {Wo_e, WoeT, 128, 128};
        pk.d[6] = {W1n,  W1nT, 128, 256}; pk.d[7] = {W1e,  W1eT, 128, 256};
        pk.d[8] = {W2n,  W2nT, 256, 128}; pk.d[9] = {W2e,  W2eT, 256, 128};
        cvt_all_k<<<dim3(128, 10), 256, 0, stream>>>(pk);
    }

    dim3 blk(256);
    const int rbN = (N + 127) / 128;
    const int rbE = (E + 127) / 128;
    const int P = (N + 255) / 256;

    // ---- CSR-by-dst build ----
    hipMemsetAsync(cur, 0, (size_t)N * sizeof(int), stream);
    count_k<<<(E + 255) / 256, blk, 0, stream>>>(eidx, cur, E);
    scan_part_k<<<P, blk, 0, stream>>>(cur, psum, N);
    scan_mid_k<<<1, 1024, 0, stream>>>(psum, P);
    scan_fin_k<<<P, blk, 0, stream>>>(cur, psum, rs, N);
    scatter_k<<<(E + 255) / 256, blk, 0, stream>>>(eidx, cur, csr, E);

    // 1) Q/K/V = LN1(node) @ {Wq,Wk,Wv} (one fused kernel)
    qkv_k<<<rbN, blk, 0, stream>>>(node, N, (const short*)WqT, (const short*)WkT,
                                   (const short*)WvT, g1n, b1n, Qb, Kb, Vb);

    // 2) EDGE MEGA: LN1(edge)->PE->score->wE->e2->LN2->FFN->e_out
    mega_k<true><<<rbE, blk, 0, stream>>>(
        edgef, edgef, E, eidx, E, Qb, Kb,
        (const short*)WeT, (const short*)WoeT, (const short*)W1eT, (const short*)W2eT,
        g1e, b1e, g2e, b2e, bo_e, wEb, oute);

    // 3) node aggregation via CSR: wVd = segsum(w*V[src]) / (segsum(w)+1e-6)
    agg_k<<<(N + 7) / 8, blk, 0, stream>>>(Vb, wEb, csr, rs, wVd, N);

    // 4) NODE MEGA: h2 = node + wVd@Wo_n + bo_n -> LN2 -> FFN -> h_out
    mega_k<false><<<rbN, blk, 0, stream>>>(
        wVd, node, N, nullptr, 0, nullptr, nullptr,
        nullptr, (const short*)WonT, (const short*)W1nT, (const short*)W2nT,
        nullptr, nullptr, g2n, b2n, bo_n, nullptr, outn);
}

// Round 8
// 867.274 us; speedup vs baseline: 1.0421x; 1.0421x over previous
//
#include <hip/hip_runtime.h>
#include <cstdint>
#include <cstddef>

#define DEVI __device__ __forceinline__

typedef __attribute__((ext_vector_type(8))) short short8;   // 8 bf16 = 4 VGPRs
typedef __attribute__((ext_vector_type(4))) float float4v;  // MFMA acc

DEVI float silu_f(float x) { return x / (1.f + __expf(-x)); }
DEVI float clip5(float x) { return fminf(fmaxf(x, -5.f), 5.f); }

DEVI unsigned short f2bf(float f) {
    union { float f; unsigned u; } x{f};
    unsigned r = x.u + 0x7FFF + ((x.u >> 16) & 1);  // RNE
    return (unsigned short)(r >> 16);
}
DEVI unsigned pack2(float a, float b) {
    return (unsigned)f2bf(a) | ((unsigned)f2bf(b) << 16);
}

// ---------------------------------------------------------------------------
// Weight pre-convert: src[K][N] fp32 -> dst[N][K] bf16 (transposed), 10 mats.
// ---------------------------------------------------------------------------
struct WDesc { const float* src; unsigned short* dst; int K; int N; };
struct WPack { WDesc d[10]; };

__global__ __launch_bounds__(256) void cvt_all_k(WPack p) {
    const WDesc w = p.d[blockIdx.y];
    const int total = w.K * w.N;
    const int ln = (w.N == 256) ? 8 : 7;  // N is 128 or 256
    const int nm = w.N - 1;
    for (int idx = blockIdx.x * 256 + threadIdx.x; idx < total; idx += gridDim.x * 256) {
        int k = idx >> ln, n = idx & nm;
        w.dst[(size_t)n * w.K + k] = f2bf(w.src[idx]);
    }
}

// ---------------------------------------------------------------------------
// Shared MFMA helpers (4-wave block, M-tile 128, N 128, per-wave 32x128).
// Acc layout: row = w*32 + mt*16 + laneq*4 + r, col = nt*16 + lanem.
// ---------------------------------------------------------------------------
template <int LDA>
DEVI void mfma64s(const short* A, const short* B, int w, int lanem, int laneq,
                  float4v acc[2][8]) {
#pragma unroll
    for (int s = 0; s < 2; s++) {
        const int ko = s * 32 + laneq * 8;
        short8 bfr[8];
#pragma unroll
        for (int nt = 0; nt < 8; nt++)
            bfr[nt] = *(const short8*)(B + (nt * 16 + lanem) * 72 + ko);
#pragma unroll
        for (int mt = 0; mt < 2; mt++) {
            short8 af = *(const short8*)(A + (w * 32 + mt * 16 + lanem) * LDA + ko);
#pragma unroll
            for (int nt = 0; nt < 8; nt++)
                acc[mt][nt] = __builtin_amdgcn_mfma_f32_16x16x32_bf16(
                    af, bfr[nt], acc[mt][nt], 0, 0, 0);
        }
    }
}

DEVI void stageB(short* Bls, const short* WT, int ldw, int koff, int sm, int h) {
    const uint4* bs = (const uint4*)(WT + (size_t)sm * ldw + koff + h * 32);
    uint4* bd = (uint4*)(Bls + sm * 72 + h * 32);
#pragma unroll
    for (int i = 0; i < 4; i++) bd[i] = bs[i];
}

// pack acc-fragment cols [ntb*16, ntb*16+64) -> A LDS (cols 0..63, stride LDA)
// ntb MUST be compile-time (callers unroll) so acc stays in VGPRs.
template <int LDA>
DEVI void packA(short* Als, const float4v a[2][8], int ntb, int w, int lanem, int laneq) {
#pragma unroll
    for (int mt = 0; mt < 2; mt++)
#pragma unroll
        for (int r = 0; r < 4; r++) {
            const int row = w * 32 + mt * 16 + laneq * 4 + r;
#pragma unroll
            for (int nt0 = 0; nt0 < 4; nt0++)
                Als[row * LDA + nt0 * 16 + lanem] = (short)f2bf(a[mt][ntb + nt0][r]);
        }
}

// ---------------------------------------------------------------------------
// QKV fused: stage LN1(node) once -> Xls, then 3 GEMMs (Wq,Wk,Wv).
// redS/redQ aliased into Bls (reads complete before first Bls stage write,
// separated by the post-LN __syncthreads).
// ---------------------------------------------------------------------------
__global__ __launch_bounds__(256, 2) void qkv_k(
    const float* __restrict__ X, int M,
    const short* __restrict__ W0, const short* __restrict__ W1, const short* __restrict__ W2,
    const float* __restrict__ g, const float* __restrict__ b,
    float* __restrict__ o0, float* __restrict__ o1, float* __restrict__ o2)
{
    __shared__ short Xls[128 * 136];
    __shared__ short Bls[128 * 72];
    float* redS = (float*)Bls;      // aliased: used only pre-first-stage
    float* redQ = redS + 256;

    const int tid = threadIdx.x, l = tid & 63, w = tid >> 6;
    const int lanem = l & 15, laneq = l >> 4;
    const int rbase = blockIdx.x * 128;
    const int sm = tid >> 1, h = tid & 1;
    const int grow = rbase + sm;
    const bool rowok = grow < M;

    // LN stats + stage (single X read: keep row-half in regs)
    {
        float4 v[16];
        const float* xr = X + (size_t)grow * 128 + h * 64;
        float s = 0.f, q = 0.f;
#pragma unroll
        for (int i = 0; i < 16; i++) {
            v[i] = rowok ? *(const float4*)(xr + i * 4) : make_float4(0.f, 0.f, 0.f, 0.f);
            s += v[i].x + v[i].y + v[i].z + v[i].w;
            q += v[i].x * v[i].x + v[i].y * v[i].y + v[i].z * v[i].z + v[i].w * v[i].w;
        }
        redS[tid] = s; redQ[tid] = q;
        __syncthreads();
        float ts = redS[sm * 2] + redS[sm * 2 + 1];
        float tq = redQ[sm * 2] + redQ[sm * 2 + 1];
        float mu = ts * (1.f / 128.f);
        float var = tq * (1.f / 128.f) - mu * mu;
        float rstd = rsqrtf(var + 1e-5f);
#pragma unroll
        for (int i = 0; i < 16; i++) {
            int c = h * 64 + i * 4;
            float4 g4 = *(const float4*)(g + c);
            float4 b4 = *(const float4*)(b + c);
            v[i].x = (v[i].x - mu) * rstd * g4.x + b4.x;
            v[i].y = (v[i].y - mu) * rstd * g4.y + b4.y;
            v[i].z = (v[i].z - mu) * rstd * g4.z + b4.z;
            v[i].w = (v[i].w - mu) * rstd * g4.w + b4.w;
        }
        uint4* xd = (uint4*)(Xls + sm * 136 + h * 64);
#pragma unroll
        for (int i = 0; i < 8; i++) {
            uint4 o;
            o.x = pack2(v[i * 2].x, v[i * 2].y);
            o.y = pack2(v[i * 2].z, v[i * 2].w);
            o.z = pack2(v[i * 2 + 1].x, v[i * 2 + 1].y);
            o.w = pack2(v[i * 2 + 1].z, v[i * 2 + 1].w);
            xd[i] = o;
        }
    }
    __syncthreads();   // redS reads + Xls writes complete before Bls staging

    const short* Ws[3] = {W0, W1, W2};
    float* outs[3] = {o0, o1, o2};
#pragma unroll
    for (int j = 0; j < 3; j++) {
        float4v acc[2][8];
#pragma unroll
        for (int mt = 0; mt < 2; mt++)
#pragma unroll
            for (int nt = 0; nt < 8; nt++) acc[mt][nt] = (float4v){0.f, 0.f, 0.f, 0.f};
#pragma unroll
        for (int k0 = 0; k0 < 128; k0 += 64) {
            stageB(Bls, Ws[j], 128, k0, sm, h);
            __syncthreads();
            mfma64s<136>(Xls + k0, Bls, w, lanem, laneq, acc);
            __syncthreads();
        }
        float* oj = outs[j];
#pragma unroll
        for (int mt = 0; mt < 2; mt++)
#pragma unroll
            for (int nt = 0; nt < 8; nt++) {
                const int gc = nt * 16 + lanem;
#pragma unroll
                for (int r = 0; r < 4; r++) {
                    int gr = rbase + w * 32 + mt * 16 + laneq * 4 + r;
                    if (gr < M) oj[(size_t)gr * 128 + gc] = acc[mt][nt][r];
                }
            }
    }
}

// ---------------------------------------------------------------------------
// MEGA kernel (round-3/7 proven structure, 4 waves, wave tile 32x128).
// EDGE=true : X=edgef. LN1 -> [pv prefetch] -> PE=@We -> score (Phase C, regs)
//             -> e2 = edgef + score@Wo + bo -> in-reg LN2 -> FFN -> e_out.
// EDGE=false: X=wVd.   h2 = node + X@Wo + bo -> in-reg LN2 -> FFN -> h_out.
// LDS-capped at 2 blocks/CU -> 2 waves/SIMD, so VGPRs up to 256 are free:
// pv[64] (QK product) and rres[64] (residual) are register-prefetched so
// their load latency drains at the pre-existing GEMM barriers.
// ---------------------------------------------------------------------------
template <bool EDGE>
__global__ __launch_bounds__(256, 2) void mega_k(
    const float* __restrict__ X, const float* __restrict__ resid, int M,
    const int* __restrict__ eidx, int E,
    const float* __restrict__ Qm, const float* __restrict__ Km,
    const short* __restrict__ WgT, const short* __restrict__ WoT,
    const short* __restrict__ W1T, const short* __restrict__ W2T,
    const float* __restrict__ g1, const float* __restrict__ b1,
    const float* __restrict__ g2, const float* __restrict__ b2,
    const float* __restrict__ bo, float* __restrict__ wE,
    float* __restrict__ out)
{
    __shared__ short Xls[128 * 136];   // A operand / staged X / staged hn
    __shared__ short Bls[128 * 72];
    float* redS = (float*)Bls;         // aliased: EDGE Phase A only
    float* redQ = redS + 256;

    const int tid = threadIdx.x, l = tid & 63, w = tid >> 6;
    const int lanem = l & 15, laneq = l >> 4;
    const int rbase = blockIdx.x * 128;
    const int sm = tid >> 1, h = tid & 1;
    const int grow = rbase + sm;
    const bool rowok = grow < M;

    float4v accS[2][8];  // EDGE: PE then score
    float4v e2a[2][8];   // proj acc -> e2/h2 -> final out (GEMM2 accumulates)
    float pv[2][4][8];   // EDGE: prefetched clip5(K*Q/4), [mt][r][nt]

    // ---- Phase A+B (EDGE): LN1 (single X read) + GEMM0 (PE = LN1(X) @ We) ----
    if constexpr (EDGE) {
        {
            float4 v[16];
            const float* xr = X + (size_t)grow * 128 + h * 64;
            float s = 0.f, q = 0.f;
#pragma unroll
            for (int i = 0; i < 16; i++) {
                v[i] = rowok ? *(const float4*)(xr + i * 4) : make_float4(0.f, 0.f, 0.f, 0.f);
                s += v[i].x + v[i].y + v[i].z + v[i].w;
                q += v[i].x * v[i].x + v[i].y * v[i].y + v[i].z * v[i].z + v[i].w * v[i].w;
            }
            redS[tid] = s; redQ[tid] = q;
            __syncthreads();
            float ts = redS[sm * 2] + redS[sm * 2 + 1];
            float tq = redQ[sm * 2] + redQ[sm * 2 + 1];
            float mu1 = ts * (1.f / 128.f);
            float var1 = tq * (1.f / 128.f) - mu1 * mu1;
            float rstd1 = rsqrtf(var1 + 1e-5f);
#pragma unroll
            for (int i = 0; i < 16; i++) {
                int c = h * 64 + i * 4;
                float4 g4 = *(const float4*)(g1 + c);
                float4 b4 = *(const float4*)(b1 + c);
                v[i].x = (v[i].x - mu1) * rstd1 * g4.x + b4.x;
                v[i].y = (v[i].y - mu1) * rstd1 * g4.y + b4.y;
                v[i].z = (v[i].z - mu1) * rstd1 * g4.z + b4.z;
                v[i].w = (v[i].w - mu1) * rstd1 * g4.w + b4.w;
            }
            uint4* xd = (uint4*)(Xls + sm * 136 + h * 64);
#pragma unroll
            for (int i = 0; i < 8; i++) {
                uint4 o;
                o.x = pack2(v[i * 2].x, v[i * 2].y);
                o.y = pack2(v[i * 2].z, v[i * 2].w);
                o.z = pack2(v[i * 2 + 1].x, v[i * 2 + 1].y);
                o.w = pack2(v[i * 2 + 1].z, v[i * 2 + 1].w);
                xd[i] = o;
            }
        }
        __syncthreads();   // redS/redQ reads done before Bls staging below

        // ---- pv prefetch: clip5(K[src]*Q[dst]/4) -> regs (independent of
        //      GEMM0; latency drains at GEMM0's barriers) ----
#pragma unroll
        for (int mt = 0; mt < 2; mt++)
#pragma unroll
            for (int r = 0; r < 4; r++) {
                const int row = w * 32 + mt * 16 + laneq * 4 + r;
                const int e = rbase + row;
                const bool ok = e < M;
                const int si = ok ? eidx[e] : 0;
                const int di = ok ? eidx[(size_t)E + e] : 0;
                const float* qr = Qm + (size_t)di * 128;
                const float* kr = Km + (size_t)si * 128;
#pragma unroll
                for (int nt = 0; nt < 8; nt++) {
                    const int gc = nt * 16 + lanem;
                    pv[mt][r][nt] = clip5(kr[gc] * qr[gc] * 0.25f);
                }
            }

#pragma unroll
        for (int mt = 0; mt < 2; mt++)
#pragma unroll
            for (int nt = 0; nt < 8; nt++) accS[mt][nt] = (float4v){0.f, 0.f, 0.f, 0.f};

#pragma unroll
        for (int k0 = 0; k0 < 128; k0 += 64) {
            stageB(Bls, WgT, 128, k0, sm, h);
            __syncthreads();
            mfma64s<136>(Xls + k0, Bls, w, lanem, laneq, accS);
            __syncthreads();
        }

        // ---- Phase C: score = pv*PE (pure VALU+shfl), wE out ----
#pragma unroll
        for (int mt = 0; mt < 2; mt++)
#pragma unroll
            for (int r = 0; r < 4; r++) {
                const int row = w * 32 + mt * 16 + laneq * 4 + r;
                const int e = rbase + row;
                const bool ok = e < M;
                float hs[8];
#pragma unroll
                for (int nt = 0; nt < 8; nt++) {
                    float sv = pv[mt][r][nt] * accS[mt][nt][r];
                    accS[mt][nt][r] = sv;
                    hs[nt] = sv;
                }
#pragma unroll
                for (int nt = 0; nt < 8; nt++) {
                    hs[nt] += __shfl_xor(hs[nt], 1, 64);
                    hs[nt] += __shfl_xor(hs[nt], 2, 64);
                    hs[nt] += __shfl_xor(hs[nt], 4, 64);
                    hs[nt] += __shfl_xor(hs[nt], 8, 64);
                }
                if (lanem == 0 && ok) {
                    float4 wa, wb;
                    wa.x = __expf(clip5(hs[0])); wa.y = __expf(clip5(hs[1]));
                    wa.z = __expf(clip5(hs[2])); wa.w = __expf(clip5(hs[3]));
                    wb.x = __expf(clip5(hs[4])); wb.y = __expf(clip5(hs[5]));
                    wb.z = __expf(clip5(hs[6])); wb.w = __expf(clip5(hs[7]));
                    *(float4*)(wE + (size_t)e * 8) = wa;
                    *(float4*)(wE + (size_t)e * 8 + 4) = wb;
                }
            }
    } else {
        // NODE: stage raw X once into Xls (both halves)
#pragma unroll
        for (int k0 = 0; k0 < 128; k0 += 64) {
            const int kb = k0 + h * 32;
            const float* xr2 = X + (size_t)grow * 128 + kb;
            float4 v[8];
#pragma unroll
            for (int i = 0; i < 8; i++)
                v[i] = rowok ? *(const float4*)(xr2 + i * 4) : make_float4(0.f, 0.f, 0.f, 0.f);
            uint4* ad = (uint4*)(Xls + sm * 136 + kb);
#pragma unroll
            for (int i = 0; i < 4; i++) {
                uint4 o;
                o.x = pack2(v[i * 2].x, v[i * 2].y);
                o.y = pack2(v[i * 2].z, v[i * 2].w);
                o.z = pack2(v[i * 2 + 1].x, v[i * 2 + 1].y);
                o.w = pack2(v[i * 2 + 1].z, v[i * 2 + 1].w);
                ad[i] = o;
            }
        }
    }

    // ---- rres prefetch: residual -> regs (latency drains at proj barriers) --
    float rres[2][8][4];
#pragma unroll
    for (int mt = 0; mt < 2; mt++)
#pragma unroll
        for (int r = 0; r < 4; r++) {
            const int gr = rbase + w * 32 + mt * 16 + laneq * 4 + r;
            const bool ok = gr < M;
#pragma unroll
            for (int nt = 0; nt < 8; nt++) {
                const int gc = nt * 16 + lanem;
                rres[mt][nt][r] = ok ? resid[(size_t)gr * 128 + gc] : 0.f;
            }
        }

    // ---- Phase D: proj GEMM (A = score [EDGE] or staged X [NODE]) @ WoT ----
#pragma unroll
    for (int mt = 0; mt < 2; mt++)
#pragma unroll
        for (int nt = 0; nt < 8; nt++) e2a[mt][nt] = (float4v){0.f, 0.f, 0.f, 0.f};

#pragma unroll
    for (int k0 = 0; k0 < 128; k0 += 64) {
        if constexpr (EDGE) {
            packA<136>(Xls, accS, k0 >> 4, w, lanem, laneq);  // cols 0..63
        }
        stageB(Bls, WoT, 128, k0, sm, h);
        __syncthreads();
        if constexpr (EDGE)
            mfma64s<136>(Xls, Bls, w, lanem, laneq, e2a);
        else
            mfma64s<136>(Xls + k0, Bls, w, lanem, laneq, e2a);
        __syncthreads();
    }

    // ---- Phase E: e2 = rres + proj + bo; in-register LN2 stats ----
    float mur[2][4], rsr[2][4];
#pragma unroll
    for (int mt = 0; mt < 2; mt++)
#pragma unroll
        for (int r = 0; r < 4; r++) {
            float s = 0.f, q = 0.f;
#pragma unroll
            for (int nt = 0; nt < 8; nt++) {
                const int gc = nt * 16 + lanem;
                float x = rres[mt][nt][r] + e2a[mt][nt][r] + bo[gc];
                e2a[mt][nt][r] = x;
                s += x; q += x * x;
            }
            s += __shfl_xor(s, 1, 64); q += __shfl_xor(q, 1, 64);
            s += __shfl_xor(s, 2, 64); q += __shfl_xor(q, 2, 64);
            s += __shfl_xor(s, 4, 64); q += __shfl_xor(q, 4, 64);
            s += __shfl_xor(s, 8, 64); q += __shfl_xor(q, 8, 64);
            float mu = s * (1.f / 128.f);
            float var = q * (1.f / 128.f) - mu * mu;
            mur[mt][r] = mu;
            rsr[mt][r] = rsqrtf(var + 1e-5f);
        }

    // ---- Phase F: pack hn = LN2(e2) fully into Xls (frees LN state) ----
#pragma unroll
    for (int mt = 0; mt < 2; mt++)
#pragma unroll
        for (int r = 0; r < 4; r++) {
            const int row = w * 32 + mt * 16 + laneq * 4 + r;
            const float muv = mur[mt][r], rv = rsr[mt][r];
#pragma unroll
            for (int nt = 0; nt < 8; nt++) {
                const int gc = nt * 16 + lanem;
                float hnv = (e2a[mt][nt][r] - muv) * rv * g2[gc] + b2[gc];
                Xls[row * 136 + gc] = (short)f2bf(hnv);
            }
        }

    // ---- GEMM1 both halves: acc2[hh] = hn @ W1half ----
    float4v acc2[2][2][8];
#pragma unroll
    for (int hh = 0; hh < 2; hh++)
#pragma unroll
        for (int mt = 0; mt < 2; mt++)
#pragma unroll
            for (int nt = 0; nt < 8; nt++) acc2[hh][mt][nt] = (float4v){0.f, 0.f, 0.f, 0.f};

#pragma unroll
    for (int hh = 0; hh < 2; hh++) {
        const short* w1b = W1T + hh * 16384;
#pragma unroll
        for (int k0 = 0; k0 < 128; k0 += 64) {
            stageB(Bls, w1b, 128, k0, sm, h);
            __syncthreads();
            mfma64s<136>(Xls + k0, Bls, w, lanem, laneq, acc2[hh]);
            __syncthreads();
        }
    }

    // silu
#pragma unroll
    for (int hh = 0; hh < 2; hh++)
#pragma unroll
        for (int mt = 0; mt < 2; mt++)
#pragma unroll
            for (int nt = 0; nt < 8; nt++)
#pragma unroll
                for (int r = 0; r < 4; r++)
                    acc2[hh][mt][nt][r] = silu_f(acc2[hh][mt][nt][r]);

    // ---- GEMM2: e2a += silu(t) @ W2 (accumulate into residual acc) ----
#pragma unroll
    for (int hh = 0; hh < 2; hh++) {
#pragma unroll
        for (int k0 = 0; k0 < 128; k0 += 64) {
            packA<136>(Xls, acc2[hh], k0 >> 4, w, lanem, laneq);  // cols 0..63
            stageB(Bls, W2T, 256, hh * 128 + k0, sm, h);
            __syncthreads();
            mfma64s<136>(Xls, Bls, w, lanem, laneq, e2a);
            __syncthreads();
        }
    }

    // ---- epilogue: out = e2a ----
#pragma unroll
    for (int mt = 0; mt < 2; mt++)
#pragma unroll
        for (int nt = 0; nt < 8; nt++) {
            const int gc = nt * 16 + lanem;
#pragma unroll
            for (int r = 0; r < 4; r++) {
                const int gr = rbase + w * 32 + mt * 16 + laneq * 4 + r;
                if (gr < M) out[(size_t)gr * 128 + gc] = e2a[mt][nt][r];
            }
        }
}

// ---------------------------------------------------------------------------
// CSR-by-dst build: count -> 2-level exclusive scan -> scatter (src,eid)
// ---------------------------------------------------------------------------
__global__ __launch_bounds__(256) void count_k(
    const int* __restrict__ eidx, int* __restrict__ deg, int E)
{
    int e = blockIdx.x * 256 + threadIdx.x;
    if (e < E) atomicAdd(&deg[eidx[(size_t)E + e]], 1);
}

__global__ __launch_bounds__(256) void scan_part_k(
    const int* __restrict__ deg, int* __restrict__ psum, int Nn)
{
    __shared__ int red[256];
    int i = blockIdx.x * 256 + threadIdx.x;
    red[threadIdx.x] = (i < Nn) ? deg[i] : 0;
    __syncthreads();
    for (int s = 128; s > 0; s >>= 1) {
        if (threadIdx.x < s) red[threadIdx.x] += red[threadIdx.x + s];
        __syncthreads();
    }
    if (threadIdx.x == 0) psum[blockIdx.x] = red[0];
}

__global__ __launch_bounds__(1024) void scan_mid_k(int* __restrict__ psum, int P)
{
    __shared__ int sm[1024];
    int t = threadIdx.x;
    int v = (t < P) ? psum[t] : 0;
    sm[t] = v;
    __syncthreads();
    for (int ofs = 1; ofs < 1024; ofs <<= 1) {
        int x = sm[t];
        if (t >= ofs) x += sm[t - ofs];
        __syncthreads();
        sm[t] = x;
        __syncthreads();
    }
    if (t < P) psum[t] = sm[t] - v;  // exclusive
}

__global__ __launch_bounds__(256) void scan_fin_k(
    int* __restrict__ deg_cur, const int* __restrict__ psum,
    int* __restrict__ rs, int Nn)
{
    __shared__ int sm[256];
    int i = blockIdx.x * 256 + threadIdx.x;
    int t = threadIdx.x;
    int v = (i < Nn) ? deg_cur[i] : 0;
    sm[t] = v;
    __syncthreads();
    for (int ofs = 1; ofs < 256; ofs <<= 1) {
        int x = sm[t];
        if (t >= ofs) x += sm[t - ofs];
        __syncthreads();
        sm[t] = x;
        __syncthreads();
    }
    if (i < Nn) {
        int excl = sm[t] - v + psum[blockIdx.x];
        rs[i] = excl;
        deg_cur[i] = excl;            // cursor for scatter
        if (i == Nn - 1) rs[Nn] = excl + v;
    }
}

__global__ __launch_bounds__(256) void scatter_k(
    const int* __restrict__ eidx, int* __restrict__ cur,
    int2* __restrict__ csr, int E)
{
    int e = blockIdx.x * 256 + threadIdx.x;
    if (e >= E) return;
    int d = eidx[(size_t)E + e];
    int pos = atomicAdd(&cur[d], 1);
    csr[pos] = make_int2(eidx[e], e);  // (src, eid)
}

// ---------------------------------------------------------------------------
// Node aggregation: per dst node, sum w*V[src] and z over its CSR edge list,
// write wV/(z+1e-6). 32 lanes/node, register accumulation, no atomics.
// ---------------------------------------------------------------------------
__global__ __launch_bounds__(256) void agg_k(
    const float* __restrict__ V, const float* __restrict__ wE,
    const int2* __restrict__ csr, const int* __restrict__ rs,
    float* __restrict__ out, int Nn)
{
    int n = blockIdx.x * 8 + (threadIdx.x >> 5);
    if (n >= Nn) return;
    int lane = threadIdx.x & 31;
    int h = lane >> 2;
    int b = rs[n], eend = rs[n + 1];
    float ax = 0.f, ay = 0.f, az = 0.f, aw = 0.f, zs = 0.f;
    for (int i = b; i < eend; i++) {
        int2 pr = csr[i];
        float w = wE[(size_t)pr.y * 8 + h];
        float4 vv = *(const float4*)(V + (size_t)pr.x * 128 + (size_t)lane * 4);
        ax += w * vv.x; ay += w * vv.y; az += w * vv.z; aw += w * vv.w;
        zs += w;
    }
    float rz = 1.f / (zs + 1e-6f);
    *(float4*)(out + (size_t)n * 128 + (size_t)lane * 4) =
        make_float4(ax * rz, ay * rz, az * rz, aw * rz);
}

// ---------------------------------------------------------------------------
extern "C" void kernel_launch(void* const* d_in, const int* in_sizes, int n_in,
                              void* d_out, int out_size, void* d_ws, size_t ws_size,
                              hipStream_t stream)
{
    const float* node  = (const float*)d_in[0];
    const float* edgef = (const float*)d_in[1];
    const int*   eidx  = (const int*)d_in[2];
    const float* Wq = (const float*)d_in[3];
    const float* Wk = (const float*)d_in[4];
    const float* Wv = (const float*)d_in[5];
    const float* We = (const float*)d_in[6];
    const float* Wo_n = (const float*)d_in[7];
    const float* bo_n = (const float*)d_in[8];
    const float* Wo_e = (const float*)d_in[9];
    const float* bo_e = (const float*)d_in[10];
    const float* W1n = (const float*)d_in[11];
    const float* W2n = (const float*)d_in[12];
    const float* W1e = (const float*)d_in[13];
    const float* W2e = (const float*)d_in[14];
    const float* g1n = (const float*)d_in[15];
    const float* b1n = (const float*)d_in[16];
    const float* g1e = (const float*)d_in[17];
    const float* b1e = (const float*)d_in[18];
    const float* g2n = (const float*)d_in[19];
    const float* b2n = (const float*)d_in[20];
    const float* g2e = (const float*)d_in[21];
    const float* b2e = (const float*)d_in[22];

    const int N = in_sizes[0] / 128;
    const int E = in_sizes[1] / 128;
    float* outn = (float*)d_out;                    // node out
    float* oute = (float*)d_out + (size_t)N * 128;  // edge out

    // ---- workspace: bf16 transposed weights first, then fp32/int buffers ----
    unsigned short* wts = (unsigned short*)d_ws;
    unsigned short* WqT  = wts;            // 128x128
    unsigned short* WkT  = wts + 16384;
    unsigned short* WvT  = wts + 32768;
    unsigned short* WeT  = wts + 49152;
    unsigned short* WonT = wts + 65536;
    unsigned short* WoeT = wts + 81920;
    unsigned short* W1nT = wts + 98304;    // 256x128
    unsigned short* W1eT = wts + 131072;   // 256x128
    unsigned short* W2nT = wts + 163840;   // 128x256
    unsigned short* W2eT = wts + 196608;   // 128x256  (end: 229376 shorts)
    float* p = (float*)(wts + 229376);
    float* Qb  = p; p += (size_t)N * 128;
    float* Kb  = p; p += (size_t)N * 128;
    float* Vb  = p; p += (size_t)N * 128;
    float* wVd = p; p += (size_t)N * 128;   // divided aggregation result
    float* wEb = p; p += (size_t)E * 8;     // per-edge per-head weights
    int* rs   = (int*)p;                    // rowstart, N+1
    int* cur  = rs + (N + 1);               // degree / scatter cursor, N
    int* psum = cur + N;                    // partial sums, up to 1024
    int* csr_i = psum + 1024;
    csr_i = (int*)(((uintptr_t)csr_i + 15) & ~(uintptr_t)15);
    int2* csr = (int2*)csr_i;               // E entries (src, eid)

    // ---- weight conversion (one launch, 10 matrices) ----
    {
        WPack pk;
        pk.d[0] = {Wq,   WqT,  128, 128}; pk.d[1] = {Wk,   WkT,  128, 128};
        pk.d[2] = {Wv,   WvT,  128, 128}; pk.d[3] = {We,   WeT,  128, 128};
        pk.d[4] = {Wo_n, WonT, 128, 128}; pk.d[5] = {Wo_e, WoeT, 128, 128};
        pk.d[6] = {W1n,  W1nT, 128, 256}; pk.d[7] = {W1e,  W1eT, 128, 256};
        pk.d[8] = {W2n,  W2nT, 256, 128}; pk.d[9] = {W2e,  W2eT, 256, 128};
        cvt_all_k<<<dim3(128, 10), 256, 0, stream>>>(pk);
    }

    dim3 blk(256);
    const int rbN = (N + 127) / 128;
    const int rbE = (E + 127) / 128;
    const int P = (N + 255) / 256;

    // ---- CSR-by-dst build ----
    hipMemsetAsync(cur, 0, (size_t)N * sizeof(int), stream);
    count_k<<<(E + 255) / 256, blk, 0, stream>>>(eidx, cur, E);
    scan_part_k<<<P, blk, 0, stream>>>(cur, psum, N);
    scan_mid_k<<<1, 1024, 0, stream>>>(psum, P);
    scan_fin_k<<<P, blk, 0, stream>>>(cur, psum, rs, N);
    scatter_k<<<(E + 255) / 256, blk, 0, stream>>>(eidx, cur, csr, E);

    // 1) Q/K/V = LN1(node) @ {Wq,Wk,Wv} (one fused kernel)
    qkv_k<<<rbN, blk, 0, stream>>>(node, N, (const short*)WqT, (const short*)WkT,
                                   (const short*)WvT, g1n, b1n, Qb, Kb, Vb);

    // 2) EDGE MEGA: LN1(edge)->PE->score->wE->e2->LN2->FFN->e_out
    mega_k<true><<<rbE, blk, 0, stream>>>(
        edgef, edgef, E, eidx, E, Qb, Kb,
        (const short*)WeT, (const short*)WoeT, (const short*)W1eT, (const short*)W2eT,
        g1e, b1e, g2e, b2e, bo_e, wEb, oute);

    // 3) node aggregation via CSR: wVd = segsum(w*V[src]) / (segsum(w)+1e-6)
    agg_k<<<(N + 7) / 8, blk, 0, stream>>>(Vb, wEb, csr, rs, wVd, N);

    // 4) NODE MEGA: h2 = node + wVd@Wo_n + bo_n -> LN2 -> FFN -> h_out
    mega_k<false><<<rbN, blk, 0, stream>>>(
        wVd, node, N, nullptr, 0, nullptr, nullptr,
        nullptr, (const short*)WonT, (const short*)W1nT, (const short*)W2nT,
        nullptr, nullptr, g2n, b2n, bo_n, nullptr, outn);
}